// Round 1
// 496.401 us; speedup vs baseline: 1.0328x; 1.0328x over previous
//
#include <hip/hip_runtime.h>
#include <hip/hip_bf16.h>

#define N_USER 100000
#define N_ITEM 100000
#define NE     300000
#define S      128

typedef __attribute__((ext_vector_type(8))) short short8;
typedef __attribute__((ext_vector_type(4))) float floatx4;
typedef unsigned long long ull;

static __device__ __forceinline__ short f2bf(float x) {
  union { float f; unsigned u; } a; a.f = x;
  unsigned r = a.u + 0x7FFFu + ((a.u >> 16) & 1u);   // RNE
  return (short)(r >> 16);
}

// ---------------- prep: wpack (blocks 0..119), zpage (120), last_edge (121..) --------
// Wp[((ks*24 + nt)*64 + lane)*8 + j] = W[col][K], col = nt*16 + (lane&15),
// K = ks*32 + (lane>>4)*8 + j.  ks<16 -> Wi[col][K]; ks>=16 -> Wh[col][K-512].
__global__ void prep_kernel(const int* __restrict__ src, const int* __restrict__ dst,
                            int* __restrict__ last_u, int* __restrict__ last_v,
                            const float* __restrict__ Wi, const float* __restrict__ Wh,
                            short* __restrict__ Wp, float* __restrict__ zpage) {
  int b = blockIdx.x;
  int tid = threadIdx.x;
  if (b < 120) {
    int id   = b * 256 + tid;                 // 30720 = 20*24*64
    int ks   = id / 1536;
    int rem  = id - ks * 1536;
    int lane = rem & 63;
    int col  = (rem >> 6) * 16 + (lane & 15);
    int kof  = (lane >> 4) * 8;
    const float* p = (ks < 16) ? (Wi + (size_t)col * 512 + ks * 32 + kof)
                               : (Wh + (size_t)col * 128 + (ks - 16) * 32 + kof);
    floatx4 a = *(const floatx4*)p;
    floatx4 c = *(const floatx4*)(p + 4);
    short8 v;
    v[0] = f2bf(a[0]); v[1] = f2bf(a[1]); v[2] = f2bf(a[2]); v[3] = f2bf(a[3]);
    v[4] = f2bf(c[0]); v[5] = f2bf(c[1]); v[6] = f2bf(c[2]); v[7] = f2bf(c[3]);
    *(short8*)(Wp + (size_t)id * 8) = v;
  } else if (b == 120) {
    if (tid < 128) zpage[tid] = 0.f;
  } else {
    int i = (b - 121) * 256 + tid;
    if (i < NE) {
      atomicMax(&last_u[src[i]], i);
      atomicMax(&last_v[dst[i]], i);
    }
  }
}

// ---------------- fused gather + MFMA GEMM + GRU -------------------------------------
// Block = 32 rows, 256 threads (4 waves). Whole K=640 A-panel staged once in 40 KB LDS
// as MFMA fragments: slot = ks*128 + rf*64 + lane holds A[rf*16+(lane&15)][ks*32+(lane>>4)*8 ..+7].
// Staging: thread t, iter it fills slot it*256+t -> lane-linear ds_write (conflict-free),
// fixed row per thread, 20 independent 32B gathers all issued before conversion.
// Wave w owns col-tiles nt = w + 4i (i=0..5) x rf=0..1 -> 16 acc tiles = 64 VGPRs.
__global__ __launch_bounds__(256, 3)
void fused_gru_kernel(const float* __restrict__ si, const float* __restrict__ sj,
                      const float* __restrict__ tt, const float* __restrict__ ef,
                      const int* __restrict__ src, const int* __restrict__ dst,
                      const float* __restrict__ bi, const float* __restrict__ bh,
                      const float* __restrict__ basis,
                      const int* __restrict__ last_u, const int* __restrict__ last_v,
                      const short* __restrict__ Wp, const float* __restrict__ zpage,
                      float* __restrict__ out) {
  __shared__ short As[20 * 2 * 64 * 8];      // 40 KB: [ks][rf][lane][8]
  __shared__ ull   Atab[32][5];              // other / own(mail) / basis / ef / own(h)
  __shared__ float Ttv[32];
  __shared__ float Tsc[32];

  const int tid  = threadIdx.x;
  const int lane = tid & 63;
  const int w    = tid >> 6;
  const int row0 = blockIdx.x * 32;

  // ---------- index phase: resolve gather pointers (one thread per row) --------------
  if (tid < 32) {
    int g = row0 + tid;
    bool isU = g < N_USER;
    int node = isU ? g : g - N_USER;
    const float* own = (isU ? si : sj) + (size_t)node * S;
    int l = isU ? last_u[node] : last_v[node];
    const float *a0, *a1, *a3; float tv, sc;
    if (l >= 0) {
      int o = isU ? dst[l] : src[l];
      a0 = (isU ? sj : si) + (size_t)o * S;
      a1 = own;
      a3 = ef + (size_t)l * S;
      tv = tt[l]; sc = 1.f;
    } else {
      a0 = zpage; a1 = zpage; a3 = zpage; tv = 0.f; sc = 0.f;
    }
    Atab[tid][0] = (ull)a0; Atab[tid][1] = (ull)a1; Atab[tid][2] = (ull)basis;
    Atab[tid][3] = (ull)a3; Atab[tid][4] = (ull)own;
    Ttv[tid] = tv; Tsc[tid] = sc;
  }
  __syncthreads();

  // ---------- staging: fixed row per thread; issue all 20 loads, then convert --------
  // slot(it) = it*256 + tid  ->  ks = 2*it + (w>>1), rf = w&1, frag-lane = lane.
  // seg = ((2*it+ksb)*32+kco)>>7 is compile-time per it (ksb only toggles ks bit 0).
  {
    const int srf = w & 1;
    const int row = srf * 16 + (lane & 15);
    const int kco = (lane >> 4) * 8;
    const int ksb = w >> 1;
    const float tv = Ttv[row], sc = Tsc[row];

    floatx4 va[10], vb[10];
    #pragma unroll
    for (int it = 0; it < 10; ++it) {
      const int seg = it >> 1;                       // 0,0,1,1,2,2,3,3,4,4
      const int ks  = it * 2 + ksb;
      const int off = ((ks & 3) * 32) + kco;         // K & 127
      const float* p = (const float*)Atab[row][seg] + off;
      va[it] = *(const floatx4*)p;
      vb[it] = *(const floatx4*)(p + 4);
    }
    #pragma unroll
    for (int it = 0; it < 10; ++it) {
      short8 v;
      if (it == 4 || it == 5) {                      // time encode segment
        v[0] = f2bf(__cosf(tv * va[it][0]) * sc); v[1] = f2bf(__cosf(tv * va[it][1]) * sc);
        v[2] = f2bf(__cosf(tv * va[it][2]) * sc); v[3] = f2bf(__cosf(tv * va[it][3]) * sc);
        v[4] = f2bf(__cosf(tv * vb[it][0]) * sc); v[5] = f2bf(__cosf(tv * vb[it][1]) * sc);
        v[6] = f2bf(__cosf(tv * vb[it][2]) * sc); v[7] = f2bf(__cosf(tv * vb[it][3]) * sc);
      } else {
        v[0] = f2bf(va[it][0]); v[1] = f2bf(va[it][1]);
        v[2] = f2bf(va[it][2]); v[3] = f2bf(va[it][3]);
        v[4] = f2bf(vb[it][0]); v[5] = f2bf(vb[it][1]);
        v[6] = f2bf(vb[it][2]); v[7] = f2bf(vb[it][3]);
      }
      *(short8*)&As[(it * 256 + tid) * 8] = v;       // lane-linear: conflict-free
    }
  }
  __syncthreads();

  // ---------- K loop: fully unrolled, 1-deep register pipeline on A and B ------------
  floatx4 acc[16];
  #pragma unroll
  for (int i = 0; i < 16; ++i) acc[i] = (floatx4){0.f, 0.f, 0.f, 0.f};

  short8 aC[2], bC[6], aN[2], bN[6];
  #pragma unroll
  for (int r2 = 0; r2 < 2; ++r2)
    aC[r2] = *(const short8*)&As[((0 * 2 + r2) * 64 + lane) * 8];
  #pragma unroll
  for (int i = 0; i < 6; ++i)
    bC[i] = *(const short8*)(Wp + (size_t)(((0 * 24) + w + 4 * i) * 64 + lane) * 8);

  #pragma unroll
  for (int ksr = 0; ksr < 20; ++ksr) {
    if (ksr < 19) {
      #pragma unroll
      for (int r2 = 0; r2 < 2; ++r2)
        aN[r2] = *(const short8*)&As[(((ksr + 1) * 2 + r2) * 64 + lane) * 8];
      #pragma unroll
      for (int i = 0; i < 6; ++i)
        bN[i] = *(const short8*)(Wp + (size_t)(((ksr + 1) * 24 + w + 4 * i) * 64 + lane) * 8);
    }
    #pragma unroll
    for (int i = 0; i < 4; ++i)
      #pragma unroll
      for (int r2 = 0; r2 < 2; ++r2)
        acc[i * 2 + r2] = __builtin_amdgcn_mfma_f32_16x16x32_bf16(aC[r2], bC[i], acc[i * 2 + r2], 0, 0, 0);
    if (ksr >= 16) {                         // K >= 512: cols 256..383 are ghn
      #pragma unroll
      for (int i = 4; i < 6; ++i)
        #pragma unroll
        for (int r2 = 0; r2 < 2; ++r2)
          acc[12 + (i - 4) * 2 + r2] = __builtin_amdgcn_mfma_f32_16x16x32_bf16(aC[r2], bC[i], acc[12 + (i - 4) * 2 + r2], 0, 0, 0);
    } else {                                 // K < 512: cols 256..383 are gin
      #pragma unroll
      for (int i = 4; i < 6; ++i)
        #pragma unroll
        for (int r2 = 0; r2 < 2; ++r2)
          acc[i * 2 + r2] = __builtin_amdgcn_mfma_f32_16x16x32_bf16(aC[r2], bC[i], acc[i * 2 + r2], 0, 0, 0);
    }
    #pragma unroll
    for (int r2 = 0; r2 < 2; ++r2) aC[r2] = aN[r2];
    #pragma unroll
    for (int i = 0; i < 6; ++i) bC[i] = bN[i];
  }

  // ---------- GRU epilogue: C/D layout col=lane&15, row=(lane>>4)*4+reg ---------------
  const int colb = lane & 15;
  const int krow = (lane >> 4) * 4;
  #pragma unroll
  for (int h = 0; h < 2; ++h) {
    int c = (w + 4 * h) * 16 + colb;         // hidden index 0..127
    float br  = bi[c]       + bh[c];
    float bz  = bi[128 + c] + bh[128 + c];
    float bni = bi[256 + c];
    float bnh = bh[256 + c];
    #pragma unroll
    for (int r2 = 0; r2 < 2; ++r2) {
      #pragma unroll
      for (int k = 0; k < 4; ++k) {
        int row = r2 * 16 + krow + k;
        int g = row0 + row;
        const float* hp = (g < N_USER) ? (si + (size_t)g * S)
                                       : (sj + (size_t)(g - N_USER) * S);
        float rpre = acc[h * 2 + r2][k]       + br;
        float zpre = acc[(2 + h) * 2 + r2][k] + bz;
        float gin  = acc[(4 + h) * 2 + r2][k] + bni;
        float ghn  = acc[12 + h * 2 + r2][k]  + bnh;
        float rg = 1.f / (1.f + __expf(-rpre));
        float zg = 1.f / (1.f + __expf(-zpre));
        float x  = gin + rg * ghn;
        float nn = 1.f - 2.f / (__expf(2.f * x) + 1.f);  // tanh, overflow-safe
        out[(size_t)g * S + c] = (1.f - zg) * nn + zg * hp[c];
      }
    }
  }
}

extern "C" void kernel_launch(void* const* d_in, const int* in_sizes, int n_in,
                              void* d_out, int out_size, void* d_ws, size_t ws_size,
                              hipStream_t stream) {
  const float* si    = (const float*)d_in[0];
  const float* sj    = (const float*)d_in[1];
  const float* tt    = (const float*)d_in[2];
  const float* ef    = (const float*)d_in[3];
  const int*   src   = (const int*)d_in[4];
  const int*   dst   = (const int*)d_in[5];
  const float* Wi    = (const float*)d_in[6];
  const float* Wh    = (const float*)d_in[7];
  const float* bi    = (const float*)d_in[8];
  const float* bh    = (const float*)d_in[9];
  const float* basis = (const float*)d_in[10];

  int*   last_u = (int*)d_ws;                                  // 400 KB
  int*   last_v = last_u + N_USER;                             // 400 KB
  float* zpage  = (float*)((char*)d_ws + 800000);              // 512 B of zeros
  short* Wp     = (short*)((char*)d_ws + (1 << 20));           // 480 KB bf16 fragments

  hipMemsetAsync(last_u, 0xFF, (size_t)(N_USER + N_ITEM) * sizeof(int), stream);
  prep_kernel<<<121 + (NE + 255) / 256, 256, 0, stream>>>(src, dst, last_u, last_v,
                                                          Wi, Wh, Wp, zpage);
  fused_gru_kernel<<<(N_USER + N_ITEM) / 32, 256, 0, stream>>>(
      si, sj, tt, ef, src, dst, bi, bh, basis, last_u, last_v, Wp, zpage, (float*)d_out);
}

// Round 2
// 484.178 us; speedup vs baseline: 1.0589x; 1.0252x over previous
//
#include <hip/hip_runtime.h>
#include <hip/hip_bf16.h>

#define N_USER 100000
#define N_ITEM 100000
#define NE     300000
#define S      128

typedef __attribute__((ext_vector_type(8))) short short8;
typedef __attribute__((ext_vector_type(4))) float floatx4;
typedef unsigned long long ull;

static __device__ __forceinline__ short f2bf(float x) {
  union { float f; unsigned u; } a; a.f = x;
  unsigned r = a.u + 0x7FFFu + ((a.u >> 16) & 1u);   // RNE
  return (short)(r >> 16);
}

// ---------------- prep: wpack (blocks 0..119), zpage (120), last_edge (121..) --------
// Wp[((ks*24 + nt)*64 + lane)*8 + j] = W[col][K], col = nt*16 + (lane&15),
// K = ks*32 + (lane>>4)*8 + j.  ks<16 -> Wi[col][K]; ks>=16 -> Wh[col][K-512].
__global__ void prep_kernel(const int* __restrict__ src, const int* __restrict__ dst,
                            int* __restrict__ last_u, int* __restrict__ last_v,
                            const float* __restrict__ Wi, const float* __restrict__ Wh,
                            short* __restrict__ Wp, float* __restrict__ zpage) {
  int b = blockIdx.x;
  int tid = threadIdx.x;
  if (b < 120) {
    int id   = b * 256 + tid;                 // 30720 = 20*24*64
    int ks   = id / 1536;
    int rem  = id - ks * 1536;
    int lane = rem & 63;
    int col  = (rem >> 6) * 16 + (lane & 15);
    int kof  = (lane >> 4) * 8;
    const float* p = (ks < 16) ? (Wi + (size_t)col * 512 + ks * 32 + kof)
                               : (Wh + (size_t)col * 128 + (ks - 16) * 32 + kof);
    floatx4 a = *(const floatx4*)p;
    floatx4 c = *(const floatx4*)(p + 4);
    short8 v;
    v[0] = f2bf(a[0]); v[1] = f2bf(a[1]); v[2] = f2bf(a[2]); v[3] = f2bf(a[3]);
    v[4] = f2bf(c[0]); v[5] = f2bf(c[1]); v[6] = f2bf(c[2]); v[7] = f2bf(c[3]);
    *(short8*)(Wp + (size_t)id * 8) = v;
  } else if (b == 120) {
    if (tid < 128) zpage[tid] = 0.f;
  } else {
    int i = (b - 121) * 256 + tid;
    if (i < NE) {
      atomicMax(&last_u[src[i]], i);
      atomicMax(&last_v[dst[i]], i);
    }
  }
}

// ---------------- fused gather + MFMA GEMM + GRU -------------------------------------
// Block = 32 rows, 256 threads (4 waves). Whole K=640 A-panel staged once in exactly
// 40 KB LDS as MFMA fragments (4 blocks/CU by LDS). Per-thread index resolve (no table,
// no extra barrier): thread owns row = (w&1)*16+(lane&15), stages 10 fragment slots
// slot = it*256+tid (lane-linear ds_write, conflict-free), in two 5-load batches so
// ~40 VGPRs of loads stay in flight.  __launch_bounds__(256,4): target 4 waves/SIMD so
// the K-loop's L2-latency on B-fragment loads is covered by TLP (4x58cyc MFMA > ~250cyc).
__global__ __launch_bounds__(256, 4)
void fused_gru_kernel(const float* __restrict__ si, const float* __restrict__ sj,
                      const float* __restrict__ tt, const float* __restrict__ ef,
                      const int* __restrict__ src, const int* __restrict__ dst,
                      const float* __restrict__ bi, const float* __restrict__ bh,
                      const float* __restrict__ basis,
                      const int* __restrict__ last_u, const int* __restrict__ last_v,
                      const short* __restrict__ Wp, const float* __restrict__ zpage,
                      float* __restrict__ out) {
  __shared__ short As[20 * 2 * 64 * 8];      // exactly 40960 B: [ks][rf][lane][8]

  const int tid  = threadIdx.x;
  const int lane = tid & 63;
  const int w    = tid >> 6;
  const int row0 = blockIdx.x * 32;

  // ---------- per-thread index resolve (8 threads share a row; L2-hit redundancy) ----
  const int srf = w & 1;
  const int row = srf * 16 + (lane & 15);
  const int kco = (lane >> 4) * 8;
  const int ksb = w >> 1;

  const int g0   = row0 + row;
  const bool isU = g0 < N_USER;
  const int node = isU ? g0 : g0 - N_USER;
  const float* own = (isU ? si : sj) + (size_t)node * S;
  const int l = isU ? last_u[node] : last_v[node];
  const float* pseg0; const float* pseg1; const float* pseg3;
  float tv, sc;
  if (l >= 0) {
    int o = isU ? dst[l] : src[l];
    pseg0 = (isU ? sj : si) + (size_t)o * S;   // other-end memory
    pseg1 = own;                               // own memory (mail copy)
    pseg3 = ef + (size_t)l * S;                // edge features
    tv = tt[l]; sc = 1.f;
  } else {
    pseg0 = zpage; pseg1 = zpage; pseg3 = zpage; tv = 0.f; sc = 0.f;
  }
  const float* pseg[5] = { pseg0, pseg1, basis, pseg3, own };

  // ---------- staging: 2 batches of 5 iters; loads issued before conversions ---------
  // slot(it) = it*256 + tid -> ks = 2*it + ksb, rf = srf; seg = it>>1 (compile-time).
  #pragma unroll
  for (int half = 0; half < 2; ++half) {
    floatx4 va[5], vb[5];
    #pragma unroll
    for (int i2 = 0; i2 < 5; ++i2) {
      const int it  = half * 5 + i2;
      const int seg = it >> 1;
      const int ks  = it * 2 + ksb;
      const int off = ((ks & 3) * 32) + kco;   // K & 127
      const float* p = pseg[seg] + off;
      va[i2] = *(const floatx4*)p;
      vb[i2] = *(const floatx4*)(p + 4);
    }
    #pragma unroll
    for (int i2 = 0; i2 < 5; ++i2) {
      const int it = half * 5 + i2;
      short8 v;
      if (it == 4 || it == 5) {                // time-encode segment: cos(t*basis)*sc
        v[0] = f2bf(__cosf(tv * va[i2][0]) * sc); v[1] = f2bf(__cosf(tv * va[i2][1]) * sc);
        v[2] = f2bf(__cosf(tv * va[i2][2]) * sc); v[3] = f2bf(__cosf(tv * va[i2][3]) * sc);
        v[4] = f2bf(__cosf(tv * vb[i2][0]) * sc); v[5] = f2bf(__cosf(tv * vb[i2][1]) * sc);
        v[6] = f2bf(__cosf(tv * vb[i2][2]) * sc); v[7] = f2bf(__cosf(tv * vb[i2][3]) * sc);
      } else {
        v[0] = f2bf(va[i2][0]); v[1] = f2bf(va[i2][1]);
        v[2] = f2bf(va[i2][2]); v[3] = f2bf(va[i2][3]);
        v[4] = f2bf(vb[i2][0]); v[5] = f2bf(vb[i2][1]);
        v[6] = f2bf(vb[i2][2]); v[7] = f2bf(vb[i2][3]);
      }
      *(short8*)&As[(it * 256 + tid) * 8] = v; // lane-linear: conflict-free
    }
  }
  __syncthreads();

  // ---------- K loop: fully unrolled natural form; compiler schedules hoisting -------
  floatx4 acc[16];
  #pragma unroll
  for (int i = 0; i < 16; ++i) acc[i] = (floatx4){0.f, 0.f, 0.f, 0.f};

  #pragma unroll
  for (int ksr = 0; ksr < 20; ++ksr) {
    short8 a0 = *(const short8*)&As[((ksr * 2 + 0) * 64 + lane) * 8];
    short8 a1 = *(const short8*)&As[((ksr * 2 + 1) * 64 + lane) * 8];
    short8 b[6];
    #pragma unroll
    for (int i = 0; i < 6; ++i)
      b[i] = *(const short8*)(Wp + (size_t)((ksr * 24 + w + 4 * i) * 64 + lane) * 8);
    #pragma unroll
    for (int i = 0; i < 4; ++i) {
      acc[i * 2 + 0] = __builtin_amdgcn_mfma_f32_16x16x32_bf16(a0, b[i], acc[i * 2 + 0], 0, 0, 0);
      acc[i * 2 + 1] = __builtin_amdgcn_mfma_f32_16x16x32_bf16(a1, b[i], acc[i * 2 + 1], 0, 0, 0);
    }
    if (ksr >= 16) {                           // K >= 512: cols 256..383 are ghn
      #pragma unroll
      for (int i = 4; i < 6; ++i) {
        acc[12 + (i - 4) * 2 + 0] = __builtin_amdgcn_mfma_f32_16x16x32_bf16(a0, b[i], acc[12 + (i - 4) * 2 + 0], 0, 0, 0);
        acc[12 + (i - 4) * 2 + 1] = __builtin_amdgcn_mfma_f32_16x16x32_bf16(a1, b[i], acc[12 + (i - 4) * 2 + 1], 0, 0, 0);
      }
    } else {                                   // K < 512: cols 256..383 are gin
      #pragma unroll
      for (int i = 4; i < 6; ++i) {
        acc[i * 2 + 0] = __builtin_amdgcn_mfma_f32_16x16x32_bf16(a0, b[i], acc[i * 2 + 0], 0, 0, 0);
        acc[i * 2 + 1] = __builtin_amdgcn_mfma_f32_16x16x32_bf16(a1, b[i], acc[i * 2 + 1], 0, 0, 0);
      }
    }
  }

  // ---------- GRU epilogue: C/D layout col=lane&15, row=(lane>>4)*4+reg ---------------
  const int colb = lane & 15;
  const int krow = (lane >> 4) * 4;
  #pragma unroll
  for (int h = 0; h < 2; ++h) {
    int c = (w + 4 * h) * 16 + colb;           // hidden index 0..127
    float br  = bi[c]       + bh[c];
    float bz  = bi[128 + c] + bh[128 + c];
    float bni = bi[256 + c];
    float bnh = bh[256 + c];
    #pragma unroll
    for (int r2 = 0; r2 < 2; ++r2) {
      #pragma unroll
      for (int k = 0; k < 4; ++k) {
        int rr = r2 * 16 + krow + k;
        int g = row0 + rr;
        const float* hp = (g < N_USER) ? (si + (size_t)g * S)
                                       : (sj + (size_t)(g - N_USER) * S);
        float rpre = acc[h * 2 + r2][k]       + br;
        float zpre = acc[(2 + h) * 2 + r2][k] + bz;
        float gin  = acc[(4 + h) * 2 + r2][k] + bni;
        float ghn  = acc[12 + h * 2 + r2][k]  + bnh;
        float rg = 1.f / (1.f + __expf(-rpre));
        float zg = 1.f / (1.f + __expf(-zpre));
        float x  = gin + rg * ghn;
        float nn = 1.f - 2.f / (__expf(2.f * x) + 1.f);  // tanh, overflow-safe
        out[(size_t)g * S + c] = (1.f - zg) * nn + zg * hp[c];
      }
    }
  }
}

extern "C" void kernel_launch(void* const* d_in, const int* in_sizes, int n_in,
                              void* d_out, int out_size, void* d_ws, size_t ws_size,
                              hipStream_t stream) {
  const float* si    = (const float*)d_in[0];
  const float* sj    = (const float*)d_in[1];
  const float* tt    = (const float*)d_in[2];
  const float* ef    = (const float*)d_in[3];
  const int*   src   = (const int*)d_in[4];
  const int*   dst   = (const int*)d_in[5];
  const float* Wi    = (const float*)d_in[6];
  const float* Wh    = (const float*)d_in[7];
  const float* bi    = (const float*)d_in[8];
  const float* bh    = (const float*)d_in[9];
  const float* basis = (const float*)d_in[10];

  int*   last_u = (int*)d_ws;                                  // 400 KB
  int*   last_v = last_u + N_USER;                             // 400 KB
  float* zpage  = (float*)((char*)d_ws + 800000);              // 512 B of zeros
  short* Wp     = (short*)((char*)d_ws + (1 << 20));           // 480 KB bf16 fragments

  hipMemsetAsync(last_u, 0xFF, (size_t)(N_USER + N_ITEM) * sizeof(int), stream);
  prep_kernel<<<121 + (NE + 255) / 256, 256, 0, stream>>>(src, dst, last_u, last_v,
                                                          Wi, Wh, Wp, zpage);
  fused_gru_kernel<<<(N_USER + N_ITEM) / 32, 256, 0, stream>>>(
      si, sj, tt, ef, src, dst, bi, bh, basis, last_u, last_v, Wp, zpage, (float*)d_out);
}